// Round 1
// baseline (528.891 us; speedup 1.0000x reference)
//
#include <hip/hip_runtime.h>
#include <hip/hip_bf16.h>

typedef __hip_bfloat16 bf16;

static constexpr float AVG_LOG_C = 2.8332133440562162f; // ln(17)

__device__ __forceinline__ unsigned int f2bf_bits(float f) {
    unsigned int u = __float_as_uint(f);
    return (u + 0x7fffu + ((u >> 16) & 1u)) >> 16;   // RNE to bf16 bits
}

// ---------------------------------------------------------------- detect + zero
// block 0: detect dtype of x by interpreting low 16 bits of each 32b word as bf16.
// other blocks: zero cnt[N].
__global__ __launch_bounds__(1024) void detect_zero_kernel(
    const unsigned int* __restrict__ xwords, int* __restrict__ flag,
    int* __restrict__ cnt, int n) {
    if (blockIdx.x == 0) {
        int tid = threadIdx.x;
        if (tid < 64) {
            int good = 0;
            for (int i = tid; i < 2048; i += 64) {
                unsigned int lo = xwords[i] & 0xffffu;
                float v = __uint_as_float(lo << 16);
                float a = fabsf(v);
                if (v == 0.0f || (a >= 1e-3f && a <= 100.0f)) good++;
            }
            for (int off = 32; off; off >>= 1) good += __shfl_xor(good, off, 64);
            if (tid == 0) *flag = (2 * good > 2048) ? 1 : 0;
        }
    } else {
        int i = (blockIdx.x - 1) * 1024 + threadIdx.x;
        if (i < n) cnt[i] = 0;
    }
}

// ---------------------------------------------------------------- convert weights
struct CvtTab {
    const void* src[16];
    float* dst[16];
    int n[16];
    int total;
};

__global__ void convert_kernel(CvtTab t, const int* __restrict__ flag) {
    int i = blockIdx.x * 256 + threadIdx.x;
    if (i >= t.total) return;
    int k = 0;
    while (i >= t.n[k]) { i -= t.n[k]; ++k; }
    float v;
    if (*flag)
        v = __bfloat162float(((const bf16*)t.src[k])[i]);
    else
        v = ((const float*)t.src[k])[i];
    t.dst[k][i] = v;
}

// ---------------------------------------------------------------- CSR build
__global__ void count_kernel(const int* __restrict__ dst, int* __restrict__ cnt, int e) {
    int i = blockIdx.x * 256 + threadIdx.x;
    if (i < e) atomicAdd(&cnt[dst[i]], 1);
}

__global__ __launch_bounds__(1024) void scan_kernel(
    const int* __restrict__ cnt, int* __restrict__ rowptr, int n) {
    __shared__ int wsum[16];
    __shared__ int carry_s;
    int tid = threadIdx.x, lane = tid & 63, wave = tid >> 6;
    if (tid == 0) { carry_s = 0; rowptr[0] = 0; }
    __syncthreads();
    for (int base = 0; base < n; base += 1024) {
        int i = base + tid;
        int s = (i < n) ? cnt[i] : 0;
        for (int off = 1; off < 64; off <<= 1) {
            int t = __shfl_up(s, (unsigned)off, 64);
            if (lane >= off) s += t;
        }
        if (lane == 63) wsum[wave] = s;
        __syncthreads();                            // (A)
        int carry = carry_s;
        if (wave == 0 && lane < 16) {
            int ws2 = wsum[lane];
            for (int off = 1; off < 16; off <<= 1) {
                int t = __shfl_up(ws2, (unsigned)off, 64);
                if (lane >= off) ws2 += t;
            }
            wsum[lane] = ws2;
        }
        __syncthreads();                            // (B)
        int woff = wave ? wsum[wave - 1] : 0;
        int incl = s + woff + carry;
        if (i < n) rowptr[i + 1] = incl;
        __syncthreads();                            // (C)
        if (tid == 1023) carry_s = incl;
    }
}

__global__ void init_cursor_kernel(const int* __restrict__ rowptr, int* __restrict__ cursor, int n) {
    int i = blockIdx.x * 256 + threadIdx.x;
    if (i < n) cursor[i] = rowptr[i];
}

__global__ void fill_kernel(const int* __restrict__ srcs, const int* __restrict__ dsts,
                            int* __restrict__ cursor, int* __restrict__ elist, int e) {
    int i = blockIdx.x * 256 + threadIdx.x;
    if (i < e) {
        int pos = atomicAdd(&cursor[dsts[i]], 1);
        elist[pos] = srcs[i];
    }
}

// ---------------------------------------------------------------- fuse postW@linW
__global__ void fuse_w_kernel(
    const float* __restrict__ postW1, const float* __restrict__ postb1,
    const float* __restrict__ linW1, const float* __restrict__ linb1,
    const float* __restrict__ postW2, const float* __restrict__ postb2,
    const float* __restrict__ linW2, const float* __restrict__ linb2,
    unsigned int* __restrict__ Wfp1, float* __restrict__ bf1,
    unsigned int* __restrict__ Wfp2, float* __restrict__ bf2) {
    const float* postW = blockIdx.y ? postW2 : postW1;
    const float* postb = blockIdx.y ? postb2 : postb1;
    const float* linW  = blockIdx.y ? linW2  : linW1;
    const float* linb  = blockIdx.y ? linb2  : linb1;
    unsigned int* Wfp  = blockIdx.y ? Wfp2 : Wfp1;
    float* bfo         = blockIdx.y ? bf2 : bf1;

    int idx = blockIdx.x * 256 + threadIdx.x;
    if (idx < 160 * 64) {
        int p = idx >> 6, c = idx & 63;
        float a0 = 0.f, a1 = 0.f;
        for (int k = 0; k < 64; ++k) {
            float lw = linW[k * 64 + c];
            a0 = fmaf(postW[(2 * p) * 64 + k], lw, a0);
            a1 = fmaf(postW[(2 * p + 1) * 64 + k], lw, a1);
        }
        Wfp[p * 64 + c] = f2bf_bits(a0) | (f2bf_bits(a1) << 16);
    }
    if (idx < 64) {
        float a = linb[idx];
        for (int k = 0; k < 64; ++k) a = fmaf(postb[k], linW[k * 64 + idx], a);
        bfo[idx] = a;
    }
}

// ---------------------------------------------------------------- stage A: h = lrelu(x@W0+b0)
__global__ __launch_bounds__(1024) void gemm_x_kernel(
    const void* __restrict__ xraw, const float* __restrict__ W0f,
    const float* __restrict__ b0f, float* __restrict__ h,
    const int* __restrict__ flag, int n) {
    __shared__ float wsh[128 * 64];   // 32 KB
    __shared__ float xsh[16][128];    // 8 KB
    for (int i = threadIdx.x; i < 128 * 64; i += 1024) wsh[i] = W0f[i];
    __syncthreads();
    int wave = __builtin_amdgcn_readfirstlane(threadIdx.x >> 6);
    int lane = threadIdx.x & 63;
    float bias = b0f[lane];
    bool fl = (*flag) != 0;
    const bf16* xb = (const bf16*)xraw;
    const float* xr = (const float*)xraw;
    for (int node = blockIdx.x * 16 + wave; node < n; node += gridDim.x * 16) {
        size_t base = (size_t)node * 128;
        if (fl) {
            xsh[wave][lane]      = __bfloat162float(xb[base + lane]);
            xsh[wave][64 + lane] = __bfloat162float(xb[base + 64 + lane]);
        } else {
            xsh[wave][lane]      = xr[base + lane];
            xsh[wave][64 + lane] = xr[base + 64 + lane];
        }
        float acc = bias;
#pragma unroll 16
        for (int k = 0; k < 128; ++k)
            acc = fmaf(xsh[wave][k], wsh[k * 64 + lane], acc);
        h[(size_t)node * 64 + lane] = acc > 0.f ? acc : 0.2f * acc;
    }
}

// ---------------------------------------------------------------- P/Q projection
// PQ[n][0:64] = h@preW[0:64]  (dst side),  PQ[n][64:128] = h@preW[64:128] (src side)
__global__ __launch_bounds__(1024) void gemm_pq_kernel(
    const float* __restrict__ h, const float* __restrict__ preW,
    float* __restrict__ PQ, int n) {
    __shared__ float wsh[128 * 64];   // 32 KB
    __shared__ float hsh[16][64];     // 4 KB
    for (int i = threadIdx.x; i < 128 * 64; i += 1024) wsh[i] = preW[i];
    __syncthreads();
    int wave = __builtin_amdgcn_readfirstlane(threadIdx.x >> 6);
    int lane = threadIdx.x & 63;
    for (int node = blockIdx.x * 16 + wave; node < n; node += gridDim.x * 16) {
        hsh[wave][lane] = h[(size_t)node * 64 + lane];
        float aP = 0.f, aQ = 0.f;
#pragma unroll 16
        for (int k = 0; k < 64; ++k) {
            float hv = hsh[wave][k];
            aP = fmaf(hv, wsh[k * 64 + lane], aP);
            aQ = fmaf(hv, wsh[(64 + k) * 64 + lane], aQ);
        }
        PQ[(size_t)node * 128 + lane] = aP;
        PQ[(size_t)node * 128 + 64 + lane] = aQ;
    }
}

// ---------------------------------------------------------------- aggregation + fused post GEMM
__global__ __launch_bounds__(1024) void agg_post_kernel(
    const float* __restrict__ PQ, const float* __restrict__ h,
    const int* __restrict__ rowptr, const int* __restrict__ elist,
    const float* __restrict__ preb, const unsigned int* __restrict__ Wfp,
    const float* __restrict__ bfo, float* __restrict__ hout, int n) {
    __shared__ unsigned int wsh[160 * 64];   // 40 KB, bf16-pair-packed [320,64]
    __shared__ float vsh[16][320];           // 20 KB
    for (int i = threadIdx.x; i < 160 * 64; i += 1024) wsh[i] = Wfp[i];
    __syncthreads();
    int wave = __builtin_amdgcn_readfirstlane(threadIdx.x >> 6);
    int lane = threadIdx.x & 63;
    float pb = preb[lane];
    float bias = bfo[lane];
    float* v = vsh[wave];
    for (int node = blockIdx.x * 16 + wave; node < n; node += gridDim.x * 16) {
        int beg = rowptr[node], end = rowptr[node + 1];
        int cnt = end - beg;
        float s = 0.f, m = -3.4e38f;
        for (int e = beg; e < end; ++e) {
            int src = elist[e];
            float q = PQ[(size_t)src * 128 + 64 + lane];
            s += q;
            m = fmaxf(m, q);
        }
        float mean, mx, deg;
        if (cnt > 0) {
            deg = (float)cnt;
            float p = PQ[(size_t)node * 128 + lane] + pb;
            mean = p + s / deg;
            mx = p + m;
        } else {
            deg = 1.f; mean = 0.f; mx = 0.f;
        }
        float att = AVG_LOG_C / logf(deg + 1.f);
        float lin = deg * (1.f / 16.f);
        v[lane]       = h[(size_t)node * 64 + lane];
        v[64 + lane]  = att * mean;
        v[128 + lane] = att * mx;
        v[192 + lane] = lin * mean;
        v[256 + lane] = lin * mx;
        float acc = bias;
#pragma unroll 8
        for (int p2 = 0; p2 < 160; ++p2) {
            unsigned int ww = wsh[p2 * 64 + lane];
            float w0 = __uint_as_float(ww << 16);
            float w1 = __uint_as_float(ww & 0xffff0000u);
            acc = fmaf(v[2 * p2], w0, acc);
            acc = fmaf(v[2 * p2 + 1], w1, acc);
        }
        hout[(size_t)node * 64 + lane] = fmaxf(acc, 0.f);   // relu
    }
}

// ---------------------------------------------------------------- final h@W2+b2
__global__ void final_kernel(const float* __restrict__ h, const float* __restrict__ W2,
                             const float* __restrict__ b2, void* __restrict__ out,
                             const int* __restrict__ flag, int n) {
    int gw = (blockIdx.x * blockDim.x + threadIdx.x) >> 6;
    int lane = threadIdx.x & 63;
    if (gw >= n) return;
    float val = h[(size_t)gw * 64 + lane] * W2[lane];
    for (int off = 32; off; off >>= 1) val += __shfl_xor(val, off, 64);
    if (lane == 0) {
        val += b2[0];
        if (*flag) ((unsigned short*)out)[gw] = (unsigned short)f2bf_bits(val);
        else       ((float*)out)[gw] = val;
    }
}

// ---------------------------------------------------------------- launch
extern "C" void kernel_launch(void* const* d_in, const int* in_sizes, int n_in,
                              void* d_out, int out_size, void* d_ws, size_t ws_size,
                              hipStream_t stream) {
    const int N = in_sizes[0] / 128;
    const int E = in_sizes[2] / 2;
    const int* ei = (const int*)d_in[2];
    const int* esrc = ei;
    const int* edst = ei + E;

    char* w = (char*)d_ws;
    auto alloc = [&](size_t bytes) -> void* {
        void* p = (void*)w;
        w += (bytes + 255) & ~(size_t)255;
        return p;
    };
    int* flag    = (int*)alloc(4);
    int* cnt     = (int*)alloc((size_t)N * 4);
    int* rowptr  = (int*)alloc((size_t)(N + 1) * 4);
    int* cursor  = (int*)alloc((size_t)N * 4);
    int* elist   = (int*)alloc((size_t)E * 4);
    float* W0f   = (float*)alloc(128 * 64 * 4);
    float* b0f   = (float*)alloc(64 * 4);
    float* pre1  = (float*)alloc(128 * 64 * 4);
    float* preb1 = (float*)alloc(64 * 4);
    float* post1 = (float*)alloc(320 * 64 * 4);
    float* postb1= (float*)alloc(64 * 4);
    float* lin1  = (float*)alloc(64 * 64 * 4);
    float* linb1 = (float*)alloc(64 * 4);
    float* pre2  = (float*)alloc(128 * 64 * 4);
    float* preb2 = (float*)alloc(64 * 4);
    float* post2 = (float*)alloc(320 * 64 * 4);
    float* postb2= (float*)alloc(64 * 4);
    float* lin2  = (float*)alloc(64 * 64 * 4);
    float* linb2 = (float*)alloc(64 * 4);
    float* W2f   = (float*)alloc(64 * 4);
    float* b2f_  = (float*)alloc(4);
    unsigned int* Wfp1 = (unsigned int*)alloc(160 * 64 * 4);
    float* bf1   = (float*)alloc(64 * 4);
    unsigned int* Wfp2 = (unsigned int*)alloc(160 * 64 * 4);
    float* bf2   = (float*)alloc(64 * 4);
    float* hA    = (float*)alloc((size_t)N * 64 * 4);
    float* hB    = (float*)alloc((size_t)N * 64 * 4);
    float* PQ    = (float*)alloc((size_t)N * 128 * 4);

    detect_zero_kernel<<<1 + (N + 1023) / 1024, 1024, 0, stream>>>(
        (const unsigned int*)d_in[0], flag, cnt, N);

    CvtTab t{};
    int ci = 0;
    auto add = [&](int di, float* dst, int nn) {
        t.src[ci] = d_in[di]; t.dst[ci] = dst; t.n[ci] = nn; ci++;
    };
    add(3, W0f, 128 * 64);  add(4, b0f, 64);
    add(5, pre1, 128 * 64); add(6, preb1, 64);
    add(7, post1, 320 * 64); add(8, postb1, 64);
    add(9, lin1, 64 * 64);  add(10, linb1, 64);
    add(11, pre2, 128 * 64); add(12, preb2, 64);
    add(13, post2, 320 * 64); add(14, postb2, 64);
    add(15, lin2, 64 * 64); add(16, linb2, 64);
    add(17, W2f, 64);       add(18, b2f_, 1);
    int total = 0;
    for (int i = 0; i < 16; ++i) total += t.n[i];
    t.total = total;
    convert_kernel<<<(total + 255) / 256, 256, 0, stream>>>(t, flag);

    count_kernel<<<(E + 255) / 256, 256, 0, stream>>>(edst, cnt, E);
    scan_kernel<<<1, 1024, 0, stream>>>(cnt, rowptr, N);
    init_cursor_kernel<<<(N + 255) / 256, 256, 0, stream>>>(rowptr, cursor, N);
    fill_kernel<<<(E + 255) / 256, 256, 0, stream>>>(esrc, edst, cursor, elist, E);
    fuse_w_kernel<<<dim3(40, 2), 256, 0, stream>>>(
        post1, postb1, lin1, linb1, post2, postb2, lin2, linb2,
        Wfp1, bf1, Wfp2, bf2);

    gemm_x_kernel<<<256, 1024, 0, stream>>>(d_in[0], W0f, b0f, hA, flag, N);

    gemm_pq_kernel<<<256, 1024, 0, stream>>>(hA, pre1, PQ, N);
    agg_post_kernel<<<512, 1024, 0, stream>>>(PQ, hA, rowptr, elist, preb1, Wfp1, bf1, hB, N);

    gemm_pq_kernel<<<256, 1024, 0, stream>>>(hB, pre2, PQ, N);
    agg_post_kernel<<<512, 1024, 0, stream>>>(PQ, hB, rowptr, elist, preb2, Wfp2, bf2, hA, N);

    final_kernel<<<(N * 64 + 255) / 256, 256, 0, stream>>>(hA, W2f, b2f_, d_out, flag, N);
}

// Round 3
// 322.924 us; speedup vs baseline: 1.6378x; 1.6378x over previous
//
#include <hip/hip_runtime.h>
#include <hip/hip_bf16.h>

typedef __hip_bfloat16 bf16;
typedef unsigned short u16;
typedef unsigned int u32;
typedef __attribute__((ext_vector_type(8))) short short8;
typedef __attribute__((ext_vector_type(4))) float f32x4;

static constexpr float AVG_LOG_C = 2.8332133440562162f; // ln(17)

__device__ __forceinline__ u32 f2bf_bits(float f) {
    u32 u = __float_as_uint(f);
    return (u + 0x7fffu + ((u >> 16) & 1u)) >> 16;   // RNE to bf16 bits
}
__device__ __forceinline__ float bf2f(u16 b) {
    return __uint_as_float(((u32)b) << 16);
}

// ---------------------------------------------------------------- detect + zero
__global__ __launch_bounds__(1024) void detect_zero_kernel(
    const u32* __restrict__ xwords, int* __restrict__ flag,
    int* __restrict__ cnt, int n) {
    if (blockIdx.x == 0) {
        int tid = threadIdx.x;
        if (tid < 64) {
            int good = 0;
            for (int i = tid; i < 2048; i += 64) {
                u32 lo = xwords[i] & 0xffffu;
                float v = __uint_as_float(lo << 16);
                float a = fabsf(v);
                if (v == 0.0f || (a >= 1e-3f && a <= 100.0f)) good++;
            }
            for (int off = 32; off; off >>= 1) good += __shfl_xor(good, off, 64);
            if (tid == 0) *flag = (2 * good > 2048) ? 1 : 0;
        }
    } else {
        int i = (blockIdx.x - 1) * 1024 + threadIdx.x;
        if (i < n) cnt[i] = 0;
    }
}

// ---------------------------------------------------------------- convert weights to f32 masters
struct CvtTab {
    const void* src[16];
    float* dst[16];
    int n[16];
    int total;
};

__global__ void convert_kernel(CvtTab t, const int* __restrict__ flag) {
    int i = blockIdx.x * 256 + threadIdx.x;
    if (i >= t.total) return;
    int k = 0;
    while (i >= t.n[k]) { i -= t.n[k]; ++k; }
    float v;
    if (*flag)
        v = __bfloat162float(((const bf16*)t.src[k])[i]);
    else
        v = ((const float*)t.src[k])[i];
    t.dst[k][i] = v;
}

// ---------------------------------------------------------------- CSR build
__global__ void count_kernel(const int* __restrict__ dst, int* __restrict__ cnt, int e) {
    int i = blockIdx.x * 256 + threadIdx.x;
    if (i < e) atomicAdd(&cnt[dst[i]], 1);
}

// hierarchical scan: pass A — 4096-entry chunks, inclusive partials + chunk sums
__global__ __launch_bounds__(1024) void scan_a_kernel(
    const int* __restrict__ cnt, int* __restrict__ rowptr,
    int* __restrict__ bsum, int n) {
    __shared__ int wsum[16];
    int tid = threadIdx.x, lane = tid & 63, wave = tid >> 6;
    int base = blockIdx.x * 4096 + tid * 4;
    int v0 = (base + 0 < n) ? cnt[base + 0] : 0;
    int v1 = (base + 1 < n) ? cnt[base + 1] : 0;
    int v2 = (base + 2 < n) ? cnt[base + 2] : 0;
    int v3 = (base + 3 < n) ? cnt[base + 3] : 0;
    int t1 = v0 + v1, t2 = t1 + v2, t3 = t2 + v3;
    int s = t3;
    for (int off = 1; off < 64; off <<= 1) {
        int t = __shfl_up(s, (unsigned)off, 64);
        if (lane >= off) s += t;
    }
    if (lane == 63) wsum[wave] = s;
    __syncthreads();
    if (wave == 0 && lane < 16) {
        int w = wsum[lane];
        for (int off = 1; off < 16; off <<= 1) {
            int t = __shfl_up(w, (unsigned)off, 64);
            if (lane >= off) w += t;
        }
        wsum[lane] = w;
    }
    __syncthreads();
    int excl = s - t3 + (wave ? wsum[wave - 1] : 0);
    if (base + 0 < n) rowptr[base + 1] = excl + v0;
    if (base + 1 < n) rowptr[base + 2] = excl + t1;
    if (base + 2 < n) rowptr[base + 3] = excl + t2;
    if (base + 3 < n) rowptr[base + 4] = excl + t3;
    if (tid == 1023) bsum[blockIdx.x] = wsum[15];
}

// pass C — add chunk offsets, finalize rowptr, init cursor
__global__ __launch_bounds__(1024) void scan_c_kernel(
    int* __restrict__ rowptr, int* __restrict__ cursor,
    const int* __restrict__ bsum, int n) {
    int j = blockIdx.x * 1024 + threadIdx.x;  // 0..n
    if (j > n) return;
    int val;
    if (j == 0) val = 0;
    else {
        int chunk = (j - 1) >> 12;
        int off = 0;
        for (int k = 0; k < chunk; ++k) off += bsum[k];
        val = rowptr[j] + off;
    }
    rowptr[j] = val;
    if (j < n) cursor[j] = val;
}

__global__ void fill_kernel(const int* __restrict__ srcs, const int* __restrict__ dsts,
                            int* __restrict__ cursor, int* __restrict__ elist, int e) {
    int i = blockIdx.x * 256 + threadIdx.x;
    if (i < e) {
        int pos = atomicAdd(&cursor[dsts[i]], 1);
        elist[pos] = srcs[i];
    }
}

// ---------------------------------------------------------------- fuse postW@linW (f32 out)
__global__ void fuse_w_kernel(
    const float* __restrict__ postW1, const float* __restrict__ postb1,
    const float* __restrict__ linW1, const float* __restrict__ linb1,
    const float* __restrict__ postW2, const float* __restrict__ postb2,
    const float* __restrict__ linW2, const float* __restrict__ linb2,
    float* __restrict__ Wf1, float* __restrict__ bfo1,
    float* __restrict__ Wf2, float* __restrict__ bfo2) {
    const float* postW = blockIdx.y ? postW2 : postW1;
    const float* postb = blockIdx.y ? postb2 : postb1;
    const float* linW  = blockIdx.y ? linW2  : linW1;
    const float* linb  = blockIdx.y ? linb2  : linb1;
    float* Wf          = blockIdx.y ? Wf2 : Wf1;
    float* bfo         = blockIdx.y ? bfo2 : bfo1;

    int idx = blockIdx.x * 256 + threadIdx.x;
    if (idx < 320 * 64) {
        int p = idx >> 6, c = idx & 63;
        float a = 0.f;
        for (int k = 0; k < 64; ++k)
            a = fmaf(postW[p * 64 + k], linW[k * 64 + c], a);
        Wf[idx] = a;
    }
    if (idx < 64) {
        float a = linb[idx];
        for (int k = 0; k < 64; ++k) a = fmaf(postb[k], linW[k * 64 + idx], a);
        bfo[idx] = a;
    }
}

// ---------------------------------------------------------------- pack weights into MFMA B-fragment order
// dst[idx], idx = (((s*NC/16 + c)*64 + lane)*8 + j)
// mode 0: src is row-major [K, NC]:           src[kk*NC + col]
// mode 1: src is pre_W [128,64], logical Wcat[64,128] (h -> [P|Q]):
//         col<64 -> src[kk*64+col], col>=64 -> src[(64+kk)*64 + (col-64)]
struct PackTab {
    const float* src[5];
    u16* dst[5];
    int NC[5];
    int sz[5];
    int mode[5];
    int total;
};

__global__ void pack_kernel(PackTab t) {
    int idx = blockIdx.x * 256 + threadIdx.x;
    if (idx >= t.total) return;
    int k = 0;
    while (idx >= t.sz[k]) { idx -= t.sz[k]; ++k; }
    int NC = t.NC[k];
    int nc16 = NC >> 4;
    int j = idx & 7, l = (idx >> 3) & 63;
    int tt = idx >> 9;
    int c = tt % nc16, s = tt / nc16;
    int kk = s * 32 + (l >> 4) * 8 + j;
    int col = c * 16 + (l & 15);
    float v;
    if (t.mode[k] == 0) {
        v = t.src[k][kk * NC + col];
    } else {
        v = (col < 64) ? t.src[k][kk * 64 + col]
                       : t.src[k][(64 + kk) * 64 + (col - 64)];
    }
    t.dst[k][idx] = (u16)f2bf_bits(v);
}

// ---------------------------------------------------------------- generic MFMA GEMM
// out[n,NCOL] = act(A[n,K] @ B[K,NCOL] + bias), A bf16 (or f32 if XMODE && !*flag),
// B pre-packed fragments, out bf16. Block = 4 waves, 64 rows/block, wave = 16 rows.
template<int K, int NCOL, int ACT, bool XMODE>   // ACT 0=none 1=lrelu 2=relu
__global__ __launch_bounds__(256) void mfma_gemm_kernel(
    const void* __restrict__ Araw, const u16* __restrict__ Bfrag,
    const float* __restrict__ bias, u16* __restrict__ out,
    const int* __restrict__ flag, int n) {
    constexpr int S = K / 32, C = NCOL / 16;
    int wave = __builtin_amdgcn_readfirstlane(threadIdx.x >> 6);
    int lane = threadIdx.x & 63;
    int rowbase = blockIdx.x * 64 + wave * 16;
    int arow = rowbase + (lane & 15);
    if (arow >= n) arow = n - 1;
    int koff = (lane >> 4) * 8;
    f32x4 acc[C];
#pragma unroll
    for (int c = 0; c < C; ++c) acc[c] = f32x4{0.f, 0.f, 0.f, 0.f};

    bool isbf = true;
    if constexpr (XMODE) isbf = (*flag != 0);

#pragma unroll
    for (int s = 0; s < S; ++s) {
        short8 a;
        if (isbf) {
            a = *(const short8*)((const u16*)Araw + (size_t)arow * K + s * 32 + koff);
        } else {
            const float* xf = (const float*)Araw + (size_t)arow * K + s * 32 + koff;
            f32x4 x0 = *(const f32x4*)xf;
            f32x4 x1 = *(const f32x4*)(xf + 4);
#pragma unroll
            for (int j = 0; j < 4; ++j) {
                a[j]     = (short)f2bf_bits(x0[j]);
                a[4 + j] = (short)f2bf_bits(x1[j]);
            }
        }
#pragma unroll
        for (int c = 0; c < C; ++c) {
            short8 b = *(const short8*)(Bfrag + ((size_t)(s * C + c) * 64 + lane) * 8);
            acc[c] = __builtin_amdgcn_mfma_f32_16x16x32_bf16(a, b, acc[c], 0, 0, 0);
        }
    }
    // C/D layout: col = lane&15, row = (lane>>4)*4 + reg
    int r0 = rowbase + (lane >> 4) * 4;
#pragma unroll
    for (int c = 0; c < C; ++c) {
        int col = c * 16 + (lane & 15);
        float bv = (ACT == 0) ? 0.f : bias[col];
#pragma unroll
        for (int r = 0; r < 4; ++r) {
            int row = r0 + r;
            if (row < n) {
                float v = acc[c][r] + bv;
                if (ACT == 1) v = v > 0.f ? v : 0.2f * v;
                if (ACT == 2) v = fmaxf(v, 0.f);
                out[(size_t)row * NCOL + col] = (u16)f2bf_bits(v);
            }
        }
    }
}

// ---------------------------------------------------------------- aggregation (gather) -> v[N,320] bf16
__global__ __launch_bounds__(256) void agg_kernel(
    const u16* __restrict__ PQ, const u16* __restrict__ h,
    const int* __restrict__ rowptr, const int* __restrict__ elist,
    const float* __restrict__ preb, u16* __restrict__ v, int n) {
    int wave = __builtin_amdgcn_readfirstlane(threadIdx.x >> 6);
    int lane = threadIdx.x & 63;
    int node = blockIdx.x * 4 + wave;
    if (node >= n) return;
    int beg = rowptr[node], end = rowptr[node + 1];
    int cnt = end - beg;
    float s = 0.f, m = -3.4e38f;
    int e = beg;
    for (; e + 4 <= end; e += 4) {
        int s0 = elist[e], s1 = elist[e + 1], s2 = elist[e + 2], s3 = elist[e + 3];
        float q0 = bf2f(PQ[(size_t)s0 * 128 + 64 + lane]);
        float q1 = bf2f(PQ[(size_t)s1 * 128 + 64 + lane]);
        float q2 = bf2f(PQ[(size_t)s2 * 128 + 64 + lane]);
        float q3 = bf2f(PQ[(size_t)s3 * 128 + 64 + lane]);
        s += (q0 + q1) + (q2 + q3);
        m = fmaxf(fmaxf(m, fmaxf(q0, q1)), fmaxf(q2, q3));
    }
    for (; e < end; ++e) {
        float q = bf2f(PQ[(size_t)elist[e] * 128 + 64 + lane]);
        s += q;
        m = fmaxf(m, q);
    }
    float mean, mx, deg;
    if (cnt > 0) {
        deg = (float)cnt;
        float p = bf2f(PQ[(size_t)node * 128 + lane]) + preb[lane];
        mean = p + s / deg;
        mx = p + m;
    } else {
        deg = 1.f; mean = 0.f; mx = 0.f;
    }
    float att = AVG_LOG_C / logf(deg + 1.f);
    float lin = deg * (1.f / 16.f);
    size_t vb = (size_t)node * 320;
    v[vb + lane]       = h[(size_t)node * 64 + lane];
    v[vb + 64 + lane]  = (u16)f2bf_bits(att * mean);
    v[vb + 128 + lane] = (u16)f2bf_bits(att * mx);
    v[vb + 192 + lane] = (u16)f2bf_bits(lin * mean);
    v[vb + 256 + lane] = (u16)f2bf_bits(lin * mx);
}

// ---------------------------------------------------------------- final h@W2+b2
__global__ __launch_bounds__(256) void final_kernel(
    const u16* __restrict__ h, const float* __restrict__ W2,
    const float* __restrict__ b2, void* __restrict__ out,
    const int* __restrict__ flag, int n) {
    int gw = (blockIdx.x * blockDim.x + threadIdx.x) >> 6;
    int lane = threadIdx.x & 63;
    if (gw >= n) return;
    float val = bf2f(h[(size_t)gw * 64 + lane]) * W2[lane];
    for (int off = 32; off; off >>= 1) val += __shfl_xor(val, off, 64);
    if (lane == 0) {
        val += b2[0];
        if (*flag) ((u16*)out)[gw] = (u16)f2bf_bits(val);
        else       ((float*)out)[gw] = val;
    }
}

// ---------------------------------------------------------------- launch
extern "C" void kernel_launch(void* const* d_in, const int* in_sizes, int n_in,
                              void* d_out, int out_size, void* d_ws, size_t ws_size,
                              hipStream_t stream) {
    const int N = in_sizes[0] / 128;
    const int E = in_sizes[2] / 2;
    const int* ei = (const int*)d_in[2];
    const int* esrc = ei;
    const int* edst = ei + E;

    char* w = (char*)d_ws;
    auto alloc = [&](size_t bytes) -> void* {
        void* p = (void*)w;
        w += (bytes + 255) & ~(size_t)255;
        return p;
    };
    int* flag    = (int*)alloc(4);
    int* cnt     = (int*)alloc((size_t)N * 4);
    int* rowptr  = (int*)alloc((size_t)(N + 1) * 4);
    int* cursor  = (int*)alloc((size_t)N * 4);
    int* bsum    = (int*)alloc(16 * 4);
    int* elist   = (int*)alloc((size_t)E * 4);
    // f32 masters
    float* W0f   = (float*)alloc(128 * 64 * 4);
    float* b0f   = (float*)alloc(64 * 4);
    float* pre1  = (float*)alloc(128 * 64 * 4);
    float* preb1 = (float*)alloc(64 * 4);
    float* post1 = (float*)alloc(320 * 64 * 4);
    float* postb1= (float*)alloc(64 * 4);
    float* lin1  = (float*)alloc(64 * 64 * 4);
    float* linb1 = (float*)alloc(64 * 4);
    float* pre2  = (float*)alloc(128 * 64 * 4);
    float* preb2 = (float*)alloc(64 * 4);
    float* post2 = (float*)alloc(320 * 64 * 4);
    float* postb2= (float*)alloc(64 * 4);
    float* lin2  = (float*)alloc(64 * 64 * 4);
    float* linb2 = (float*)alloc(64 * 4);
    float* W2f   = (float*)alloc(64 * 4);
    float* b2f_  = (float*)alloc(4);
    // fused post@lin f32
    float* Wf1   = (float*)alloc(320 * 64 * 4);
    float* bfo1  = (float*)alloc(64 * 4);
    float* Wf2   = (float*)alloc(320 * 64 * 4);
    float* bfo2  = (float*)alloc(64 * 4);
    // packed bf16 B-fragments
    u16* W0p     = (u16*)alloc(128 * 64 * 2);
    u16* pre1p   = (u16*)alloc(64 * 128 * 2);
    u16* pre2p   = (u16*)alloc(64 * 128 * 2);
    u16* wf1p    = (u16*)alloc(320 * 64 * 2);
    u16* wf2p    = (u16*)alloc(320 * 64 * 2);
    // activations (bf16)
    u16* hA      = (u16*)alloc((size_t)N * 64 * 2);
    u16* hB      = (u16*)alloc((size_t)N * 64 * 2);
    u16* PQ      = (u16*)alloc((size_t)N * 128 * 2);
    u16* vbuf    = (u16*)alloc((size_t)N * 320 * 2);

    detect_zero_kernel<<<1 + (N + 1023) / 1024, 1024, 0, stream>>>(
        (const u32*)d_in[0], flag, cnt, N);

    CvtTab t{};
    int ci = 0;
    auto add = [&](int di, float* dst, int nn) {
        t.src[ci] = d_in[di]; t.dst[ci] = dst; t.n[ci] = nn; ci++;
    };
    add(3, W0f, 128 * 64);  add(4, b0f, 64);
    add(5, pre1, 128 * 64); add(6, preb1, 64);
    add(7, post1, 320 * 64); add(8, postb1, 64);
    add(9, lin1, 64 * 64);  add(10, linb1, 64);
    add(11, pre2, 128 * 64); add(12, preb2, 64);
    add(13, post2, 320 * 64); add(14, postb2, 64);
    add(15, lin2, 64 * 64); add(16, linb2, 64);
    add(17, W2f, 64);       add(18, b2f_, 1);
    int total = 0;
    for (int i = 0; i < 16; ++i) total += t.n[i];
    t.total = total;
    convert_kernel<<<(total + 255) / 256, 256, 0, stream>>>(t, flag);

    fuse_w_kernel<<<dim3(80, 2), 256, 0, stream>>>(
        post1, postb1, lin1, linb1, post2, postb2, lin2, linb2,
        Wf1, bfo1, Wf2, bfo2);

    PackTab pt{};
    pt.src[0] = W0f;  pt.dst[0] = W0p;   pt.NC[0] = 64;  pt.sz[0] = 128 * 64; pt.mode[0] = 0;
    pt.src[1] = pre1; pt.dst[1] = pre1p; pt.NC[1] = 128; pt.sz[1] = 64 * 128; pt.mode[1] = 1;
    pt.src[2] = pre2; pt.dst[2] = pre2p; pt.NC[2] = 128; pt.sz[2] = 64 * 128; pt.mode[2] = 1;
    pt.src[3] = Wf1;  pt.dst[3] = wf1p;  pt.NC[3] = 64;  pt.sz[3] = 320 * 64; pt.mode[3] = 0;
    pt.src[4] = Wf2;  pt.dst[4] = wf2p;  pt.NC[4] = 64;  pt.sz[4] = 320 * 64; pt.mode[4] = 0;
    pt.total = pt.sz[0] + pt.sz[1] + pt.sz[2] + pt.sz[3] + pt.sz[4];
    pack_kernel<<<(pt.total + 255) / 256, 256, 0, stream>>>(pt);

    count_kernel<<<(E + 255) / 256, 256, 0, stream>>>(edst, cnt, E);
    scan_a_kernel<<<(N + 4095) / 4096, 1024, 0, stream>>>(cnt, rowptr, bsum, N);
    scan_c_kernel<<<(N + 1024) / 1024, 1024, 0, stream>>>(rowptr, cursor, bsum, N);
    fill_kernel<<<(E + 255) / 256, 256, 0, stream>>>(esrc, edst, cursor, elist, E);

    int gblocks = (N + 63) / 64;
    // h = lrelu(x @ W0 + b0)
    mfma_gemm_kernel<128, 64, 1, true><<<gblocks, 256, 0, stream>>>(
        d_in[0], W0p, b0f, hA, flag, N);

    // layer 1
    mfma_gemm_kernel<64, 128, 0, false><<<gblocks, 256, 0, stream>>>(
        hA, pre1p, nullptr, PQ, flag, N);
    agg_kernel<<<(N + 3) / 4, 256, 0, stream>>>(PQ, hA, rowptr, elist, preb1, vbuf, N);
    mfma_gemm_kernel<320, 64, 2, false><<<gblocks, 256, 0, stream>>>(
        vbuf, wf1p, bfo1, hB, flag, N);

    // layer 2
    mfma_gemm_kernel<64, 128, 0, false><<<gblocks, 256, 0, stream>>>(
        hB, pre2p, nullptr, PQ, flag, N);
    agg_kernel<<<(N + 3) / 4, 256, 0, stream>>>(PQ, hB, rowptr, elist, preb2, vbuf, N);
    mfma_gemm_kernel<320, 64, 2, false><<<gblocks, 256, 0, stream>>>(
        vbuf, wf2p, bfo2, hA, flag, N);

    final_kernel<<<(N + 3) / 4, 256, 0, stream>>>(hA, W2f, b2f_, d_out, flag, N);
}